// Round 9
// baseline (113.552 us; speedup 1.0000x reference)
//
#include <hip/hip_runtime.h>
#include <hip/hip_bf16.h>

// ---------------------------------------------------------------------------
// LossNet: x (12288,128) fp32 -> scalar loss.  bsz=4096.
// 5 matrices (zx/zy folded into colsums of xz/yz):
//   task 0 xx, 1 yy, 2 xy, 3 xz (+colsum->s_zx), 4 yz (+colsum->s_zy)
// Fragment-native layout (R6): every MFMA A/B fragment is ONE coalesced
// global_load_dwordx4; no LDS staging, no per-tile barriers.
// R9: 256x256 block (R8's minimal-VMEM shape) but 16-col SUBTILE pipeline:
//   per subtile: 4 B-frag loads (double-buffered 1 ahead) -> 16 MFMAs
//   (acc live = 16 VGPR) -> immediate 16-exp epilogue.  R8 post-mortem:
//   VGPR ~220 capped residency at 2 waves/SIMD and coarse phases serialized
//   matrix/trans pipes -> pinned at ~500 TF across R1/R6/R7/R8 structures.
//   This cuts VGPR to ~150 (3 waves/SIMD) and lets MFMA(s+1) overlap
//   epilogue(s) within a wave.
// exp = __builtin_amdgcn_exp2f on prescaled inputs (1 inst).
// All reductions exclusive non-atomic stores (R3: atomics serialized).
// Timed-window floor: harness poison fill of d_ws = ~42us fixed.
// ---------------------------------------------------------------------------

typedef __attribute__((ext_vector_type(8))) short short8;   // 8 x bf16
typedef __attribute__((ext_vector_type(4))) float floatx4;  // MFMA acc

#define D   128
#define BSZ 4096
#define GPM 256          // 16-row groups per matrix (4096/16)
// expsim grid: 5 tasks x 16 rb(256 rows) x 16 cb(256 cols)
#define GRID_EXPSIM (5 * 16 * 16)

// ---------------------------------------------------------------------------
// Kernel 1: row-normalize fp32 -> bf16 into fragment-native layout,
// prescaled by sqrt(10*log2(e)).  One wave per row.  Also zeroes out[0].
// ---------------------------------------------------------------------------
__global__ __launch_bounds__(256) void normalize_kernel(
    const float* __restrict__ x, __hip_bfloat162* __restrict__ xnf2,
    float* __restrict__ out, int rows) {
  int tid = threadIdx.x;
  if (blockIdx.x == 0 && tid == 0) out[0] = 0.0f;

  int row  = blockIdx.x * 4 + (tid >> 6);
  int lane = tid & 63;
  if (row >= rows) return;
  const float2* xr = (const float2*)(x + (size_t)row * D);
  float2 v = xr[lane];
  float s = v.x * v.x + v.y * v.y;
#pragma unroll
  for (int off = 1; off < 64; off <<= 1) s += __shfl_xor(s, off, 64);
  // sqrt(10 / ln 2): dot(a,b) = 10*log2(e)*cos -> e^(10 cos) = exp2(dot)
  float scale = 3.7982825470322528f / fmaxf(sqrtf(s), 1e-12f);
  __hip_bfloat162 h;
  h.x = __float2bfloat16(v.x * scale);
  h.y = __float2bfloat16(v.y * scale);
  // fragment-native scatter: k0 = lane*2
  // short idx = g*2048 + kk*512 + (quad*16 + (row&15))*8 + j   (as bf162: /2)
  int g    = row >> 4;
  int kk   = lane >> 4;            // k0>>5
  int quad = (lane >> 2) & 3;      // (k0>>3)&3
  int jj   = lane & 3;             // (k0&7)/2
  xnf2[g * 1024 + kk * 256 + (quad * 16 + (row & 15)) * 4 + jj] = h;
}

// ---------------------------------------------------------------------------
// Subtile epilogue: 16 exps, rowsum adds, optional colsum scalar, optional
// diag.  C/D layout: col=lm, row=quad*4+reg  [m89-verified].  For a 16-col
// subtile each lane owns exactly one column (lm), so colsum is one scalar.
// ---------------------------------------------------------------------------
template <bool COL, bool DIAG>
__device__ __forceinline__ void epi_sub(
    const floatx4 (&acc)[4], float (&rs)[4][4], float& cs,
    int rowg0, int colg0, int quad, int lm, float* __restrict__ diag_ptr) {
#pragma unroll
  for (int mi = 0; mi < 4; mi++) {
#pragma unroll
    for (int r = 0; r < 4; r++) {
      float e = __builtin_amdgcn_exp2f(acc[mi][r]);  // v_exp_f32
      rs[mi][r] += e;
      if (COL) cs += e;
      if (DIAG) {
        int rowg = rowg0 + mi * 16 + quad * 4 + r;
        if (colg0 + lm == rowg) diag_ptr[rowg] = e;
      }
    }
  }
}

// ---------------------------------------------------------------------------
// Kernel 2: exp-sim, barrier-free subtile pipeline.  block = (task, rb, cb)
// covering 256x256; wave w owns rows rb*256+w*64..+64 across 16 subtiles
// of 16 cols each.
// NOTE: plain __launch_bounds__(256) — min-waves cap spills (R2).
// ---------------------------------------------------------------------------
__global__ __launch_bounds__(256) void expsim_kernel(
    const short8* __restrict__ xnf8,
    float* __restrict__ srow,   // [5][16][4096] exclusive
    float* __restrict__ scol,   // [2][16][4096] exclusive
    float* __restrict__ diag) { // [5][4096] exclusive
  __shared__ float csLDS[4 * 256];   // colsum accum, tasks 3-4 only

  int tid = threadIdx.x;
  int bx  = blockIdx.x;
  int task = bx >> 8;          // 256 blocks per task
  int rem  = bx & 255;
  int rb   = rem >> 4;         // 16 row-blocks of 256
  int cb   = rem & 15;         // 16 col-blocks of 256

  const int aoff_t[5] = {0, 1, 0, 0, 1};
  const int boff_t[5] = {0, 1, 1, 2, 2};
  bool col_en = (task >= 3);

  int w    = tid >> 6;
  int lane = tid & 63;
  int quad = lane >> 4;
  int lm   = lane & 15;
  int rowg0 = rb * 256 + w * 64;

  bool dgblk = (rb == cb);   // wave w's diagonal subtiles are s>>2 == w

  float* diag_ptr = diag + task * BSZ;

  // ---- A fragments (one coalesced b128 each), resident whole wave ----
  int gA = aoff_t[task] * GPM + rb * 16 + w * 4;
  short8 afrag[4][4];
#pragma unroll
  for (int mi = 0; mi < 4; mi++)
#pragma unroll
    for (int kk = 0; kk < 4; kk++)
      afrag[mi][kk] = xnf8[(size_t)(gA + mi) * 256 + kk * 64 + lane];

  float rs[4][4];
#pragma unroll
  for (int mi = 0; mi < 4; mi++)
#pragma unroll
    for (int r = 0; r < 4; r++) rs[mi][r] = 0.0f;

  const floatx4 z4 = {0.f, 0.f, 0.f, 0.f};
  const short8* bbase = xnf8 + (size_t)(boff_t[task] * GPM + cb * 16) * 256 + lane;

  // ---- 16 subtiles (16 cols each), double-buffered B fragments ----
  short8 bf0[4], bf1[4];
#pragma unroll
  for (int kk = 0; kk < 4; kk++) bf0[kk] = bbase[(size_t)kk * 64];

#pragma unroll
  for (int s = 0; s < 16; s++) {
    // prefetch subtile s+1 into the other buffer (independent of s's MFMAs)
    if (s < 15) {
      if ((s & 1) == 0) {
#pragma unroll
        for (int kk = 0; kk < 4; kk++)
          bf1[kk] = bbase[(size_t)(s + 1) * 256 + kk * 64];
      } else {
#pragma unroll
        for (int kk = 0; kk < 4; kk++)
          bf0[kk] = bbase[(size_t)(s + 1) * 256 + kk * 64];
      }
    }
    const short8(&bf)[4] = (s & 1) ? bf1 : bf0;

    floatx4 acc[4];
#pragma unroll
    for (int kk = 0; kk < 4; kk++)
#pragma unroll
      for (int mi = 0; mi < 4; mi++)
        acc[mi] = __builtin_amdgcn_mfma_f32_16x16x32_bf16(
            afrag[mi][kk], bf[kk], (kk == 0) ? z4 : acc[mi], 0, 0, 0);

    int colg0 = cb * 256 + s * 16;
    float cs = 0.f;
    bool dg = dgblk && ((s >> 2) == w);   // wave-uniform
    if (col_en) {
      if (dg) epi_sub<true, true>(acc, rs, cs, rowg0, colg0, quad, lm, diag_ptr);
      else    epi_sub<true, false>(acc, rs, cs, rowg0, colg0, quad, lm, diag_ptr);
      // reduce this wave's 64 rows (across quads); each slot written once
      cs += __shfl_xor(cs, 16, 64);
      cs += __shfl_xor(cs, 32, 64);
      if (quad == 0) csLDS[w * 256 + s * 16 + lm] = cs;
    } else {
      if (dg) epi_sub<false, true>(acc, rs, cs, rowg0, colg0, quad, lm, diag_ptr);
      else    epi_sub<false, false>(acc, rs, cs, rowg0, colg0, quad, lm, diag_ptr);
    }
  }

  // ---- row-sum flush: reduce over lm within quad, exclusive store ----
  float* srow_ptr = srow + ((size_t)(task * 16 + cb)) * BSZ;
#pragma unroll
  for (int mi = 0; mi < 4; mi++) {
#pragma unroll
    for (int r = 0; r < 4; r++) {
      float v = rs[mi][r];
      v += __shfl_xor(v, 1, 64);
      v += __shfl_xor(v, 2, 64);
      v += __shfl_xor(v, 4, 64);
      v += __shfl_xor(v, 8, 64);
      if (lm == 0) srow_ptr[rowg0 + mi * 16 + quad * 4 + r] = v;
    }
  }

  // ---- col-sum flush: one barrier, cross-wave LDS reduce, exclusive ----
  if (col_en) {
    __syncthreads();
    float* scol_ptr = scol + ((size_t)((task - 3) * 16 + rb)) * BSZ + cb * 256;
    scol_ptr[tid] = csLDS[tid] + csLDS[256 + tid] + csLDS[512 + tid] + csLDS[768 + tid];
  }
}

// ---------------------------------------------------------------------------
// Kernel 3: final loss reduction.  16 blocks x 256 threads, one row each.
// ---------------------------------------------------------------------------
__global__ __launch_bounds__(256) void reduce_kernel(
    const float* __restrict__ srow, const float* __restrict__ scol,
    const float* __restrict__ diag, float* __restrict__ out) {
  int tid = threadIdx.x;
  int i   = blockIdx.x * 256 + tid;

  float s[5];
#pragma unroll
  for (int t = 0; t < 5; t++) {
    float a = 0.f;
#pragma unroll
    for (int js = 0; js < 16; js++) a += srow[(size_t)(t * 16 + js) * BSZ + i];
    s[t] = a;
  }
  float s_zx = 0.f, s_zy = 0.f;
#pragma unroll 8
  for (int ib = 0; ib < 16; ib++) {
    s_zx += scol[(size_t)ib * BSZ + i];
    s_zy += scol[(size_t)(16 + ib) * BSZ + i];
  }
  float d_xx = diag[0 * BSZ + i], d_yy = diag[1 * BSZ + i];
  float d_xy = diag[2 * BSZ + i], d_ax = diag[3 * BSZ + i];
  float d_ay = diag[4 * BSZ + i];

  float denom = (s[2] - d_xy) + (s[0] - d_xx) + (s[1] - d_yy);
  float tloc = -2.0f * __logf(d_xy / denom);
  tloc -= __logf(d_ax / (s[3] - d_ax));
  tloc -= __logf(d_ay / (s[4] - d_ay));
  tloc -= __logf(d_ax / (s_zx - d_ax));   // d_zx == d_ax
  tloc -= __logf(d_ay / (s_zy - d_ay));   // d_zy == d_ay

  __shared__ float red[256];
  red[tid] = tloc;
  __syncthreads();
  for (int st = 128; st > 0; st >>= 1) {
    if (tid < st) red[tid] += red[tid + st];
    __syncthreads();
  }
  if (tid == 0) atomicAdd(out, red[0] / (float)BSZ);
}

// ---------------------------------------------------------------------------
extern "C" void kernel_launch(void* const* d_in, const int* in_sizes, int n_in,
                              void* d_out, int out_size, void* d_ws, size_t ws_size,
                              hipStream_t stream) {
  const float* x = (const float*)d_in[0];
  int rows = in_sizes[0] / D;   // 12288

  char*  ws       = (char*)d_ws;
  short* xnf      = (short*)ws;                        // 12288*128 bf16: 3 MiB
  size_t xn_bytes = (size_t)rows * D * sizeof(short);
  float* srow     = (float*)(ws + xn_bytes);           // [5][16][4096]: 1.25 MiB
  float* scol     = srow + 5 * 16 * BSZ;               // [2][16][4096]: 512 KiB
  float* diag     = scol + 2 * 16 * BSZ;               // [5][4096]: 80 KiB

  normalize_kernel<<<rows / 4, 256, 0, stream>>>(
      x, (__hip_bfloat162*)xnf, (float*)d_out, rows);
  expsim_kernel<<<GRID_EXPSIM, 256, 0, stream>>>(
      (const short8*)xnf, srow, scol, diag);
  reduce_kernel<<<16, 256, 0, stream>>>(srow, scol, diag, (float*)d_out);
}

// Round 10
// 96.070 us; speedup vs baseline: 1.1820x; 1.1820x over previous
//
#include <hip/hip_runtime.h>
#include <hip/hip_bf16.h>

// ---------------------------------------------------------------------------
// LossNet: x (12288,128) fp32 -> scalar loss.  bsz=4096.
// 5 matrices (zx/zy folded into colsums of xz/yz):
//   task 0 xx, 1 yy, 2 xy, 3 xz (+colsum->s_zx), 4 yz (+colsum->s_zy)
// Fragment-native layout (R6): every MFMA A/B fragment is ONE coalesced
// global_load_dwordx4; no LDS staging, no hot-loop barriers.
// R10: software-pipelined subtile loop.  R1-R9 post-mortem: ~500 TF plateau
// across ALL memory structures; limiter = per-wave phase serialization
// (MFMA burst, then exp burst; v_exp ~8cyc/wave-inst quarter-rate).  Fix:
// 16-col subtiles, epilogue(s-1) interleaved with MFMA(s) (independent ->
// trans+matrix pipes co-issue within one wave), 32-row waves for VGPR<=130
// (4 waves/SIMD), compact #pragma unroll 1 loop, block's 4 waves share the
// same B strip (L1 reuse).
// All reductions exclusive non-atomic stores (R3: atomics serialized).
// Timed-window floor: harness poison fill of d_ws = ~42us fixed.
// ---------------------------------------------------------------------------

typedef __attribute__((ext_vector_type(8))) short short8;   // 8 x bf16
typedef __attribute__((ext_vector_type(4))) float floatx4;  // MFMA acc

#define D   128
#define BSZ 4096
// expsim grid: 5 tasks x 32 rb(128 rows) x 8 cb(512 cols) = 1280 blocks
#define GRID_EXPSIM (5 * 32 * 8)

// ---------------------------------------------------------------------------
// Kernel 1: row-normalize fp32 -> bf16 into fragment-native layout,
// prescaled by sqrt(10*log2(e)).  One wave per row.  Also zeroes out[0].
// ---------------------------------------------------------------------------
__global__ __launch_bounds__(256) void normalize_kernel(
    const float* __restrict__ x, __hip_bfloat162* __restrict__ xnf2,
    float* __restrict__ out, int rows) {
  int tid = threadIdx.x;
  if (blockIdx.x == 0 && tid == 0) out[0] = 0.0f;

  int row  = blockIdx.x * 4 + (tid >> 6);
  int lane = tid & 63;
  if (row >= rows) return;
  const float2* xr = (const float2*)(x + (size_t)row * D);
  float2 v = xr[lane];
  float s = v.x * v.x + v.y * v.y;
#pragma unroll
  for (int off = 1; off < 64; off <<= 1) s += __shfl_xor(s, off, 64);
  // sqrt(10 / ln 2): dot(a,b) = 10*log2(e)*cos -> e^(10 cos) = exp2(dot)
  float scale = 3.7982825470322528f / fmaxf(sqrtf(s), 1e-12f);
  __hip_bfloat162 h;
  h.x = __float2bfloat16(v.x * scale);
  h.y = __float2bfloat16(v.y * scale);
  // fragment-native scatter: k0 = lane*2
  // short idx = g*2048 + kk*512 + (quad*16 + (row&15))*8 + j   (as bf162: /2)
  int g    = row >> 4;
  int kk   = lane >> 4;            // k0>>5
  int quad = (lane >> 2) & 3;      // (k0>>3)&3
  int jj   = lane & 3;             // (k0&7)/2
  xnf2[g * 1024 + kk * 256 + (quad * 16 + (row & 15)) * 4 + jj] = h;
}

// ---------------------------------------------------------------------------
// 16-col subtile epilogue for a 32-row wave: 8 exps, rowsum adds, optional
// colsum (quad-reduce -> LDS slot, written once), diag when st==st0+mi.
// C/D layout: col=lm, row=quad*4+reg  [m89-verified]
// ---------------------------------------------------------------------------
template <bool COL>
__device__ __forceinline__ void epi16(
    const floatx4 (&ac)[2], float (&rs)[2][4], int st,
    bool dgw, int st0, int rowg0, int quad, int lm, int w,
    float* __restrict__ diag_ptr, float* __restrict__ csLDS) {
  float cs = 0.f;
#pragma unroll
  for (int mi = 0; mi < 2; mi++) {
    bool dd = dgw && (st == st0 + mi);   // wave-uniform
#pragma unroll
    for (int r = 0; r < 4; r++) {
      float e = __builtin_amdgcn_exp2f(ac[mi][r]);  // v_exp_f32
      rs[mi][r] += e;
      if (COL) cs += e;
      if (dd && lm == quad * 4 + r)
        diag_ptr[rowg0 + mi * 16 + quad * 4 + r] = e;
    }
  }
  if (COL) {
    cs += __shfl_xor(cs, 16, 64);
    cs += __shfl_xor(cs, 32, 64);
    if (quad == 0) csLDS[w * 512 + st * 16 + lm] = cs;
  }
}

#define MFMA8(AC, BF)                                                        \
  _Pragma("unroll") for (int kk = 0; kk < 4; kk++)                           \
      _Pragma("unroll") for (int mi = 0; mi < 2; mi++)                       \
          AC[mi] = __builtin_amdgcn_mfma_f32_16x16x32_bf16(                  \
              afrag[mi][kk], BF[kk], (kk == 0) ? z4 : AC[mi], 0, 0, 0);

// ---------------------------------------------------------------------------
// Wave main loop: 32 rows x 512 cols as 32 subtiles of 16 cols, software-
// pipelined (epi of s-1 between MFMAs of s / loads of s+1).
// ---------------------------------------------------------------------------
template <bool COL>
__device__ __forceinline__ void wave_loop(
    const short8* __restrict__ xnf8, int gA, int gB0, int rowg0,
    int st0, bool dgw, int quad, int lm, int w, int lane,
    float (&rs)[2][4], float* __restrict__ diag_ptr,
    float* __restrict__ csLDS) {
  const floatx4 z4 = {0.f, 0.f, 0.f, 0.f};

  short8 afrag[2][4];
#pragma unroll
  for (int mi = 0; mi < 2; mi++)
#pragma unroll
    for (int kk = 0; kk < 4; kk++)
      afrag[mi][kk] = xnf8[(size_t)(gA + mi) * 256 + kk * 64 + lane];

  const short8* bp = xnf8 + (size_t)gB0 * 256 + lane;
  short8 bf0[4], bf1[4];
#pragma unroll
  for (int kk = 0; kk < 4; kk++) bf0[kk] = bp[kk * 64];
#pragma unroll
  for (int kk = 0; kk < 4; kk++) bf1[kk] = bp[256 + kk * 64];

  floatx4 ac0[2], ac1[2];
  MFMA8(ac0, bf0)   // st 0

#pragma unroll 1
  for (int k = 0; k < 15; k++) {
    int sB = 2 * k + 2;
    MFMA8(ac1, bf1)   // st sB-1
#pragma unroll
    for (int kk = 0; kk < 4; kk++) bf0[kk] = bp[(size_t)sB * 256 + kk * 64];
    epi16<COL>(ac0, rs, sB - 2, dgw, st0, rowg0, quad, lm, w, diag_ptr, csLDS);
    MFMA8(ac0, bf0)   // st sB
#pragma unroll
    for (int kk = 0; kk < 4; kk++) bf1[kk] = bp[(size_t)(sB + 1) * 256 + kk * 64];
    epi16<COL>(ac1, rs, sB - 1, dgw, st0, rowg0, quad, lm, w, diag_ptr, csLDS);
  }
  // tail: st 31 from bf1; epi st 30 (ac0), st 31 (ac1)
  MFMA8(ac1, bf1)
  epi16<COL>(ac0, rs, 30, dgw, st0, rowg0, quad, lm, w, diag_ptr, csLDS);
  epi16<COL>(ac1, rs, 31, dgw, st0, rowg0, quad, lm, w, diag_ptr, csLDS);
}

// ---------------------------------------------------------------------------
// Kernel 2: exp-sim.  block = (task, rb of 128 rows, cb of 512 cols);
// wave w owns rows rb*128+w*32..+32, all 512 cols.  4 waves share B (L1).
// NOTE: plain __launch_bounds__(256) — min-waves cap spills (R2).
// ---------------------------------------------------------------------------
__global__ __launch_bounds__(256) void expsim_kernel(
    const short8* __restrict__ xnf8,
    float* __restrict__ srow,   // [5][128][8][32] exclusive
    float* __restrict__ scol,   // [2][32][4096] exclusive
    float* __restrict__ diag) { // [5][4096] exclusive
  __shared__ float csLDS[4 * 512];   // colsum accum, tasks 3-4 only

  int tid = threadIdx.x;
  int bx  = blockIdx.x;
  int task = bx >> 8;          // 256 blocks per task
  int rem  = bx & 255;
  int rb   = rem >> 3;         // 32 row-blocks of 128
  int cb   = rem & 7;          // 8 col-strips of 512

  const int aoff_t[5] = {0, 1, 0, 0, 1};
  const int boff_t[5] = {0, 1, 1, 2, 2};
  bool col_en = (task >= 3);

  int w    = tid >> 6;
  int lane = tid & 63;
  int quad = lane >> 4;
  int lm   = lane & 15;
  int rowg0 = rb * 128 + w * 32;

  int gA  = aoff_t[task] * 256 + rb * 8 + w * 2;
  int gB0 = boff_t[task] * 256 + cb * 32;
  int st0 = rb * 8 + w * 2 - cb * 32;   // diag subtile (mi=0) if in range
  bool dgw = (st0 >= 0 && st0 < 32);

  float* diag_ptr = diag + task * BSZ;

  float rs[2][4];
#pragma unroll
  for (int mi = 0; mi < 2; mi++)
#pragma unroll
    for (int r = 0; r < 4; r++) rs[mi][r] = 0.0f;

  if (col_en)
    wave_loop<true>(xnf8, gA, gB0, rowg0, st0, dgw, quad, lm, w, lane, rs,
                    diag_ptr, csLDS);
  else
    wave_loop<false>(xnf8, gA, gB0, rowg0, st0, dgw, quad, lm, w, lane, rs,
                     diag_ptr, csLDS);

  // ---- row-sum flush: reduce over lm within quad, exclusive store ----
  float* sp = srow + (((size_t)task * 128 + rb * 4 + w) * 8 + cb) * 32;
#pragma unroll
  for (int mi = 0; mi < 2; mi++) {
#pragma unroll
    for (int r = 0; r < 4; r++) {
      float v = rs[mi][r];
      v += __shfl_xor(v, 1, 64);
      v += __shfl_xor(v, 2, 64);
      v += __shfl_xor(v, 4, 64);
      v += __shfl_xor(v, 8, 64);
      if (lm == 0) sp[mi * 16 + quad * 4 + r] = v;
    }
  }

  // ---- col-sum flush: one barrier, cross-wave LDS reduce, exclusive ----
  if (col_en) {
    __syncthreads();
    float* scp = scol + ((size_t)((task - 3) * 32 + rb)) * BSZ + cb * 512;
    for (int c = tid; c < 512; c += 256)
      scp[c] = csLDS[c] + csLDS[512 + c] + csLDS[1024 + c] + csLDS[1536 + c];
  }
}

// ---------------------------------------------------------------------------
// Kernel 3: final loss reduction.  16 blocks x 256 threads, one row each.
// ---------------------------------------------------------------------------
__global__ __launch_bounds__(256) void reduce_kernel(
    const float* __restrict__ srow, const float* __restrict__ scol,
    const float* __restrict__ diag, float* __restrict__ out) {
  int tid = threadIdx.x;
  int i   = blockIdx.x * 256 + tid;
  int strip = i >> 5, rloc = i & 31;

  float s[5];
#pragma unroll
  for (int t = 0; t < 5; t++) {
    float a = 0.f;
#pragma unroll
    for (int cb = 0; cb < 8; cb++)
      a += srow[(((size_t)t * 128 + strip) * 8 + cb) * 32 + rloc];
    s[t] = a;
  }
  float s_zx = 0.f, s_zy = 0.f;
#pragma unroll 8
  for (int rb = 0; rb < 32; rb++) {
    s_zx += scol[(size_t)rb * BSZ + i];
    s_zy += scol[(size_t)(32 + rb) * BSZ + i];
  }
  float d_xx = diag[0 * BSZ + i], d_yy = diag[1 * BSZ + i];
  float d_xy = diag[2 * BSZ + i], d_ax = diag[3 * BSZ + i];
  float d_ay = diag[4 * BSZ + i];

  float denom = (s[2] - d_xy) + (s[0] - d_xx) + (s[1] - d_yy);
  float tloc = -2.0f * __logf(d_xy / denom);
  tloc -= __logf(d_ax / (s[3] - d_ax));
  tloc -= __logf(d_ay / (s[4] - d_ay));
  tloc -= __logf(d_ax / (s_zx - d_ax));   // d_zx == d_ax
  tloc -= __logf(d_ay / (s_zy - d_ay));   // d_zy == d_ay

  __shared__ float red[256];
  red[tid] = tloc;
  __syncthreads();
  for (int st = 128; st > 0; st >>= 1) {
    if (tid < st) red[tid] += red[tid + st];
    __syncthreads();
  }
  if (tid == 0) atomicAdd(out, red[0] / (float)BSZ);
}

// ---------------------------------------------------------------------------
extern "C" void kernel_launch(void* const* d_in, const int* in_sizes, int n_in,
                              void* d_out, int out_size, void* d_ws, size_t ws_size,
                              hipStream_t stream) {
  const float* x = (const float*)d_in[0];
  int rows = in_sizes[0] / D;   // 12288

  char*  ws       = (char*)d_ws;
  short* xnf      = (short*)ws;                        // 12288*128 bf16: 3 MiB
  size_t xn_bytes = (size_t)rows * D * sizeof(short);
  float* srow     = (float*)(ws + xn_bytes);           // [5][128][8][32]: 640 KiB
  float* scol     = srow + 5 * 128 * 8 * 32;           // [2][32][4096]: 1 MiB
  float* diag     = scol + 2 * 32 * BSZ;               // [5][4096]: 80 KiB

  normalize_kernel<<<rows / 4, 256, 0, stream>>>(
      x, (__hip_bfloat162*)xnf, (float*)d_out, rows);
  expsim_kernel<<<GRID_EXPSIM, 256, 0, stream>>>(
      (const short8*)xnf, srow, scol, diag);
  reduce_kernel<<<16, 256, 0, stream>>>(srow, scol, diag, (float*)d_out);
}